// Round 7
// baseline (117.970 us; speedup 1.0000x reference)
//
#include <hip/hip_runtime.h>
#include <hip/hip_bf16.h>
#include <stdint.h>

// VQ-VAE vector quantizer forward, MI355X (gfx950).
// z: [32,256,32,32] fp32 (NCHW), E: [1024,256] fp32.
// score(n,k) = 0.5*||e_k||^2 - <f_n,e_k>  (argmin-equivalent to d2)
// dots via bf16 MFMA 16x16x32 fp32-accum; gather exact fp32.
//
// R12: R11 skeleton (BK=128, 8 chunks, proven 46us) + the traffic-halving
// register-block retried with clean codegen. Main-loop floor = per-CU LDS
// B-reads: R11 had 8 waves x 512KB (full codebook each) = 4MB/CU ~20.5us
// at 85B/cyc. Now wave = (rg=w&3: 32 rows) x (h=w>>2: code half): each B
// fragment feeds 2 MFMAs, per-CU B traffic 2MB. R7/R10 tried this and
// died on registers (R7: needed ~90 VGPR, compiler capped at 64 -> spill).
// Fix: flattened a0[8]/a1[8], all-static indexing, __launch_bounds__(512,2)
// (2 waves/SIMD -> 256-VGPR cap). MFMA count, dc-chain order and global
// tie-break order unchanged -> scores/argmin bit-identical.

typedef short v8s __attribute__((ext_vector_type(8)));
typedef float v4f __attribute__((ext_vector_type(4)));

__device__ inline unsigned short f2bf(float f) {  // RNE fp32->bf16
    uint32_t u = __float_as_uint(f);
    return (unsigned short)((u + 0x7fffu + ((u >> 16) & 1u)) >> 16);
}

// ---- Kernel 1: E -> SWIZZLED Ebf bf16 + nE + accum/done=0 ------------------
// Unit for (k, dc, g): U = (k>>4)*512 + dc*64 + g*16 + (k&15),
// holding elems d = dc*32 + g*8 .. +8. Coalesced 16B stores.
__global__ __launch_bounds__(256) void k_prep_e(const float* __restrict__ E,
                                                v8s* __restrict__ Esw,
                                                float* __restrict__ nE,
                                                float* __restrict__ accum,
                                                unsigned* __restrict__ done) {
    __shared__ float Ef[16][264];
    int q = blockIdx.x, tid = threadIdx.x;
    const float4* Ein = (const float4*)(E + ((size_t)q << 12));
#pragma unroll
    for (int i = 0; i < 4; i++) {
        int f4 = i * 256 + tid;
        int row = f4 >> 6, c4 = (f4 & 63) << 2;
        *(float4*)&Ef[row][c4] = Ein[f4];
    }
    __syncthreads();
    {
        int c = tid >> 4, l = tid & 15;
        float s = 0.f;
#pragma unroll
        for (int j = 0; j < 16; j++) { float v = Ef[c][l + 16 * j]; s += v * v; }
#pragma unroll
        for (int off = 1; off < 16; off <<= 1) s += __shfl_xor(s, off);
        if (l == 0) nE[q * 16 + c] = 0.5f * s;
    }
#pragma unroll
    for (int i = 0; i < 2; i++) {
        int u = tid + i * 256;
        int um = u & 15, ug = (u >> 4) & 3, udc = (u >> 6) & 7;
        int d0 = udc * 32 + ug * 8;
        union { v8s v; unsigned short s[8]; } pk;
#pragma unroll
        for (int e = 0; e < 8; e++) pk.s[e] = f2bf(Ef[um][d0 + e]);
        Esw[((size_t)q << 9) + u] = pk.v;
    }
    if (q == 0 && tid == 0) { accum[0] = 0.f; done[0] = 0u; }
}

// ---- Kernel 2: fused transpose+GEMM+argmin+gather+output+loss ---------------
__global__ __launch_bounds__(512, 2) void k_main(
        const v8s* __restrict__ Esw,
        const float* __restrict__ nE,
        const float* __restrict__ z,
        const float* __restrict__ E,
        float* __restrict__ out,
        float* __restrict__ accum,
        unsigned* __restrict__ done) {
    __shared__ union {
        v8s    B[2][4096];          // 2 x 64 KB double-buffer (A-tile 64KB fits)
        float4 Eg4[2048];           // epilogue swizzled tile (32 KB)
    } S;
    __shared__ float nEl[1024];
    __shared__ unsigned long long pairLds[128][2];
    __shared__ float nrmLds[128];
    __shared__ int   idxLds[128];
    __shared__ float w8[2];

    int tid = threadIdx.x;
    int lane = tid & 63, w = tid >> 6;         // 8 waves
    int g = lane >> 4, m = lane & 15;          // MFMA lane coords
    int rg = w & 3, h = w >> 2;                // 32-row group, code half
    int R0 = blockIdx.x << 7;                  // 128 rows/block
    int b = R0 >> 10, hw0 = R0 & 1023;

    // ---- A-prep: z[b][0..256][hw0..hw0+128] -> swizzled bf16 LDS tile ------
    // Thread (q=tid&31, dblk=tid>>5) loads 16 d-rows x float4 at hw quad 4q,
    // repacks to 8 v8s (4 rows x 2 slots). Swizzle slot^((row^row>>2)&7)
    // spreads both writes and fragment reads across all 8 bank-quads.
    {
        int q = tid & 31, dblk = tid >> 5;     // hw = hw0+4q, d base = dblk*16
        const float* zp = z + ((size_t)b << 18) + hw0 + (q << 2);
#pragma unroll
        for (int s = 0; s < 2; s++) {
            float4 L[8];
#pragma unroll
            for (int j = 0; j < 8; j++)
                L[j] = *(const float4*)(zp + (size_t)(((dblk << 4) + (s << 3) + j) << 10));
            const float* Lf = (const float*)L;
            int slot = (dblk << 1) + s;
#pragma unroll
            for (int c = 0; c < 4; c++) {
                union { v8s v; unsigned short u[8]; } pk;
#pragma unroll
                for (int j = 0; j < 8; j++) pk.u[j] = f2bf(Lf[j * 4 + c]);
                int row = (q << 2) + c;
                int sw = slot ^ ((row ^ (row >> 2)) & 7);
                *(v8s*)((char*)&S + (row << 9) + (sw << 4)) = pk.v;
            }
        }
    }
#pragma unroll
    for (int i = 0; i < 2; i++) nEl[tid + i * 512] = nE[tid + i * 512];
    __syncthreads();                           // A-tile resident

    // A frags: 32 rows/wave (2 M-tiles, flattened regs); norms (h==0 waves).
    v8s a0[8], a1[8];
    {
        int row0 = (rg << 5) + m;
        int row1 = row0 + 16;
        int f0 = (row0 ^ (row0 >> 2)) & 7;
        int f1 = (row1 ^ (row1 >> 2)) & 7;
#pragma unroll
        for (int dc = 0; dc < 8; dc++) {
            a0[dc] = *(const v8s*)((const char*)&S + (row0 << 9) + ((((dc << 2) + g) ^ f0) << 4));
            a1[dc] = *(const v8s*)((const char*)&S + (row1 << 9) + ((((dc << 2) + g) ^ f1) << 4));
        }
        if (h == 0) {
            float n0 = 0.f, n1 = 0.f;
#pragma unroll
            for (int dc = 0; dc < 8; dc++) {
                union { v8s v; unsigned short u[8]; } u0, u1;
                u0.v = a0[dc]; u1.v = a1[dc];
#pragma unroll
                for (int j = 0; j < 8; j++) {
                    float v0 = __uint_as_float((uint32_t)u0.u[j] << 16);
                    float v1 = __uint_as_float((uint32_t)u1.u[j] << 16);
                    n0 = fmaf(v0, v0, n0);
                    n1 = fmaf(v1, v1, n1);
                }
            }
            n0 += __shfl_xor(n0, 16); n0 += __shfl_xor(n0, 32);
            n1 += __shfl_xor(n1, 16); n1 += __shfl_xor(n1, 32);
            if (g == 0) { nrmLds[row0] = n0; nrmLds[row1] = n1; }
        }
    }
    __syncthreads();                           // A-tile consumed; S free for B

    // contiguous staging: chunk = 4096 v8s (64 KB); thread stages j*512+tid
#define STAGE(ch, buf)                                                        \
    {                                                                         \
        _Pragma("unroll")                                                     \
        for (int j = 0; j < 8; j++) {                                         \
            __builtin_amdgcn_global_load_lds(                                 \
                (const __attribute__((address_space(1))) void*)               \
                    (Esw + ((size_t)(ch) << 12) + (j << 9) + (w << 6) + lane),\
                (__attribute__((address_space(3))) void*)                     \
                    &S.B[buf][(j << 9) + (w << 6)],                           \
                16, 0, 0);                                                    \
        }                                                                     \
    }

    float best0[4], best1[4]; int bidx0[4], bidx1[4];
#pragma unroll
    for (int r = 0; r < 4; r++) {
        best0[r] = 3.4e38f; bidx0[r] = 0;
        best1[r] = 3.4e38f; bidx1[r] = 0;
    }

    STAGE(0, 0);
#pragma unroll 2
    for (int ct = 0; ct < 8; ct++) {
        int cur = ct & 1;                      // static after unroll 2
        __syncthreads();                       // chunk ct resident
        if (ct < 7) STAGE(ct + 1, cur ^ 1);
        float ne[4];
#pragma unroll
        for (int t = 0; t < 4; t++) ne[t] = nEl[(ct << 7) + (h << 6) + (t << 4) + m];
        v4f acc0[4], acc1[4];
#pragma unroll
        for (int t = 0; t < 4; t++) {
            acc0[t] = (v4f){0.f, 0.f, 0.f, 0.f};
            acc1[t] = (v4f){0.f, 0.f, 0.f, 0.f};
        }
#pragma unroll
        for (int dc = 0; dc < 8; dc++) {       // 8 indep chains/wave
#pragma unroll
            for (int t = 0; t < 4; t++) {
                v8s bf = S.B[cur][((h << 2) + t) * 512 + dc * 64 + g * 16 + m];
                acc0[t] = __builtin_amdgcn_mfma_f32_16x16x32_bf16(a0[dc], bf, acc0[t], 0, 0, 0);
                acc1[t] = __builtin_amdgcn_mfma_f32_16x16x32_bf16(a1[dc], bf, acc1[t], 0, 0, 0);
            }
        }
#pragma unroll
        for (int t = 0; t < 4; t++) {          // ascending code: tie -> low idx
            int code = (ct << 7) + (h << 6) + (t << 4) + m;
#pragma unroll
            for (int r = 0; r < 4; r++) {
                float s0 = ne[t] - acc0[t][r];
                if (s0 < best0[r]) { best0[r] = s0; bidx0[r] = code; }
                float s1 = ne[t] - acc1[t][r];
                if (s1 < best1[r]) { best1[r] = s1; bidx1[r] = code; }
            }
        }
    }

    // per-half winner reduce over 16 code-columns (pack: min => low score,
    // low idx); halves meet in pairLds.
#pragma unroll
    for (int r = 0; r < 4; r++) {
        uint32_t sb0 = __float_as_uint(best0[r]);
        sb0 = (sb0 & 0x80000000u) ? ~sb0 : (sb0 | 0x80000000u);
        unsigned long long pk0 = ((unsigned long long)sb0 << 32) | (uint32_t)bidx0[r];
        uint32_t sb1 = __float_as_uint(best1[r]);
        sb1 = (sb1 & 0x80000000u) ? ~sb1 : (sb1 | 0x80000000u);
        unsigned long long pk1 = ((unsigned long long)sb1 << 32) | (uint32_t)bidx1[r];
#pragma unroll
        for (int off = 1; off < 16; off <<= 1) {
            unsigned long long o0 = __shfl_xor(pk0, off);
            if (o0 < pk0) pk0 = o0;
            unsigned long long o1 = __shfl_xor(pk1, off);
            if (o1 < pk1) pk1 = o1;
        }
        if (m == 0) {                          // C/D row = g*4 + r
            pairLds[(rg << 5) + (g << 2) + r][h] = pk0;
            pairLds[(rg << 5) + 16 + (g << 2) + r][h] = pk1;
        }
    }
    __syncthreads();                           // winners visible; B free

    // combine halves + loss (waves 0-1): ||e* - z||^2 = 2*s* + ||z||^2.
    if (tid < 128) {
        unsigned long long p0 = pairLds[tid][0], p1 = pairLds[tid][1];
        unsigned long long pk = p1 < p0 ? p1 : p0;
        idxLds[tid] = (int)(pk & 0xffffffffu);
        uint32_t t = (uint32_t)(pk >> 32);
        float sc = __uint_as_float((t & 0x80000000u) ? (t & 0x7fffffffu) : ~t);
        float ls = 2.0f * sc + nrmLds[tid];
#pragma unroll
        for (int off = 1; off < 64; off <<= 1) ls += __shfl_xor(ls, off);
        if (lane == 0) w8[w] = ls;
    }
    __syncthreads();                           // idxLds visible for epilogue

    // epilogue: gather E rows + coalesced NCHW writes via XOR-swizzled tile.
    float* ob = out + ((size_t)b << 18);
    int hwl = tid & 31, dq0 = tid >> 5;        // dq0: 0..15
#pragma unroll 1
    for (int ph = 0; ph < 4; ph++) {
#pragma unroll
        for (int i = 0; i < 4; i++) {          // rows w + 8i (wave-uniform)
            int row = w + (i << 3);
            int k = idxLds[(ph << 5) + row];
            float4 v = ((const float4*)(E + ((size_t)k << 8)))[lane];
            S.Eg4[(row << 6) + (lane ^ row)] = v;
        }
        __syncthreads();
        int hwp = hw0 + (ph << 5) + hwl;
#pragma unroll
        for (int i = 0; i < 4; i++) {
            int dq = dq0 + (i << 4);
            float4 ev = S.Eg4[(hwl << 6) + (dq ^ hwl)];
            size_t o = ((size_t)dq << 12) + hwp;        // (4*dq)*1024 + hwp
            ob[o] = ev.x; ob[o + 1024] = ev.y; ob[o + 2048] = ev.z; ob[o + 3072] = ev.w;
        }
        __syncthreads();                        // tile reused next phase
    }

    // loss accumulate + fused scalar epilogue (last block writes outputs).
    if (tid == 0) {
        atomicAdd(accum, w8[0] + w8[1]);
        __threadfence();
        unsigned old = atomicAdd(done, 1u);
        if (old == 255u) {
            float s = atomicAdd(accum, 0.f) * (1.0f / 8388608.0f);
            out[8388608] = 1.25f * s;
            out[8388609] = s;
            out[8388610] = s;
        }
    }
#undef STAGE
}

extern "C" void kernel_launch(void* const* d_in, const int* in_sizes, int n_in,
                              void* d_out, int out_size, void* d_ws, size_t ws_size,
                              hipStream_t stream) {
    const float* z = (const float*)d_in[0];
    const float* E = (const float*)d_in[1];
    char* ws = (char*)d_ws;
    v8s*      Esw   = (v8s*)(ws);                // 524,288 B
    float*    nE    = (float*)(ws + 524288);     //   4,096 B
    float*    accum = (float*)(ws + 528384);     //       4 B
    unsigned* done  = (unsigned*)(ws + 528388);  //       4 B
    float* out = (float*)d_out;

    hipLaunchKernelGGL(k_prep_e, dim3(64),  dim3(256), 0, stream, E, Esw, nE, accum, done);
    hipLaunchKernelGGL(k_main,   dim3(256), dim3(512), 0, stream,
                       Esw, nE, z, E, out, accum, done);
}